// Round 4
// baseline (270.090 us; speedup 1.0000x reference)
//
#include <hip/hip_runtime.h>
#include <math.h>

#define NS 1000
#define NV 200
#define NF 5
#define NK 80
#define EPSF 1e-5f

// fp32(2*pi); reference wraps with jnp.mod(x, 2pi) in f32.
#define TWOPI_F 6.28318530717958647692f
// fp32(2*pi/16) -- the scan multiplies fp32(j) by this constant.
#define STEP_F  0.39269908169872414f

static __device__ __forceinline__ float frcp(float v) {
    return __builtin_amdgcn_rcpf(v);
}

// 4 blocks per sample (rotation quarters), 128 threads (2 waves).
// CODEGEN NOTE (R2/R3 post-mortem): phase 2 keeps ~85 VGPRs live (50 fp32
// accumulators + temps). __launch_bounds__ with a min-waves hint (R3:
// (256,4) -> VGPR=40) or a 512-thread block (R2: VGPR=48) makes the
// allocator spill acc to scratch: 91us -> 218/204us, WRITE_SIZE 1.5->17MB.
// Use plain __launch_bounds__(128) exactly like R1 (VGPR=84, no spill) and
// scale parallelism with MORE BLOCKS only.
//   thread = (q, jl, tp): q = tid>>5 vertex quarter (50 v), jl = (tid>>3)&3
//   local rotation (global j = jq*4 + jl), tp = tid&7 theta-pair.
// Phase 1: per-vertex tables -> LDS (12 floats per vertex).
// Phase 2: accumulate desc quarter-partials, 50 fp32 regs per thread.
// Phase 3: zero desc LDS, merge vertex-quarters via ds_add_f32.
// Phase 4: thread = (f, jo-quad), 100 active: cf = desc . W, max over the
//          4 local rotations, +b, relu, merge rotation-blocks via int
//          atomicMax on out (post-relu vals >= 0: int order == float order;
//          memset-0 and 0xAA poison both lose as signed int).
__global__ __launch_bounds__(128) void lsres_fused(
        const float* __restrict__ x,
        const float* __restrict__ mu_rho,
        const float* __restrict__ sigma_rho,
        const float* __restrict__ mu_theta,
        const float* __restrict__ sigma_theta,
        const float* __restrict__ Wc,
        const float* __restrict__ bc,
        float* __restrict__ out) {
    // 2400 floats = 9.6 KB: phase-1/2 vertex tables (600 float4); after
    // phase 2 the first 1600 floats are reused as desc[4][5][80].
    __shared__ float smem[2400];
    float4* smem4 = (float4*)smem;

    const int bid = blockIdx.x;
    const int s   = bid >> 2;
    const int jq  = bid & 3;           // rotation quarter 0..3
    const int tid = threadIdx.x;
    const int q   = tid >> 5;          // vertex quarter 0..3
    const int jl  = (tid >> 3) & 3;    // local rotation 0..3
    const int tp  = tid & 7;           // theta-pair 0..7
    const int t0  = tp * 2;            // theta bins t0, t0+1
    const int jg  = jq * 4 + jl;       // global rotation 0..15

    // --- per-thread constants (theta-bin Gaussians; F rows are identical) ---
    const float mu0 = mu_theta[t0];
    const float mu1 = mu_theta[t0 + 1];
    const float sg0 = sigma_theta[t0];
    const float sg1 = sigma_theta[t0 + 1];
    const float ist0 = 1.0f / (sg0 * sg0 + EPSF);
    const float ist1 = 1.0f / (sg1 * sg1 + EPSF);
    const float joff = (float)jg * STEP_F;

    float mr[5], isr[5];
#pragma unroll
    for (int r = 0; r < 5; ++r) {
        mr[r] = mu_rho[r * 16];           // mu_rho[k] depends only on r = k/16
        float sr = sigma_rho[r * 16];
        isr[r] = 1.0f / (sr * sr + EPSF);
    }

    // --- Phase 1: vertex tables ---
    for (int v = tid; v < NV; v += 128) {
        const float* xe = x + ((size_t)s * NV + v) * 8;
        float4 x0 = *(const float4*)(xe);       // feat0..3
        float4 x1 = *(const float4*)(xe + 4);   // feat4, rho, theta, mask
        float rho = x1.y, theta = x1.z, mask = x1.w;
        float rg[5];
        float srg = 0.0f;
#pragma unroll
        for (int r = 0; r < 5; ++r) {
            float d = rho - mr[r];
            rg[r] = __expf(-d * d * isr[r]);
            srg += rg[r];
        }
        // act_norm = mask*Rg*T / (mask*sumRg*sumT + eps); fold mask into feat
        // and into the denominator term.
        smem4[v * 3 + 0] = make_float4(x0.x * mask, x0.y * mask, x0.z * mask, x0.w * mask);
        smem4[v * 3 + 1] = make_float4(x1.x * mask, rg[0], rg[1], rg[2]);
        smem4[v * 3 + 2] = make_float4(rg[3], rg[4], mask * srg, theta);
    }
    __syncthreads();

    // --- Phase 2: accumulate desc partials over this quarter's vertices ---
    float acc[5][5][2];
#pragma unroll
    for (int f = 0; f < 5; ++f)
#pragma unroll
        for (int r = 0; r < 5; ++r) {
            acc[f][r][0] = 0.0f;
            acc[f][r][1] = 0.0f;
        }

    const int vbase = q * (NV / 4);
    for (int vi = 0; vi < NV / 4; ++vi) {
        const int v = vbase + vi;
        float4 a  = smem4[v * 3 + 0];   // fm0..3       (broadcast-ish reads)
        float4 bv = smem4[v * 3 + 1];   // fm4, rg0..2
        float4 c  = smem4[v * 3 + 2];   // rg3, rg4, mask*sumRg, theta

        // th = mod(theta + j*step, 2pi); theta < 2pi, joff < 2pi, so one
        // conditional subtract reproduces the reference's f32 wrap decision.
        float th = c.w + joff;
        th = (th >= TWOPI_F) ? (th - TWOPI_F) : th;

        float d0 = th - mu0;
        float d1 = th - mu1;
        float T0 = __expf(-d0 * d0 * ist0);
        float T1 = __expf(-d1 * d1 * ist1);

        // sum of T over the 16 theta bins of rotation jg
        // (8-lane tp-group, 2 bins each; xor 1/2/4 stays inside the group)
        float sT = T0 + T1;
        sT += __shfl_xor(sT, 1);
        sT += __shfl_xor(sT, 2);
        sT += __shfl_xor(sT, 4);

        float inv = frcp(fmaf(c.z, sT, EPSF));
        float p0 = T0 * inv;
        float p1 = T1 * inv;

        float fm[5] = {a.x, a.y, a.z, a.w, bv.x};
        float rg[5] = {bv.y, bv.z, bv.w, c.x, c.y};
#pragma unroll
        for (int r = 0; r < 5; ++r) {
            float g0 = rg[r] * p0;
            float g1 = rg[r] * p1;
#pragma unroll
            for (int f = 0; f < 5; ++f) {
                acc[f][r][0] = fmaf(fm[f], g0, acc[f][r][0]);
                acc[f][r][1] = fmaf(fm[f], g1, acc[f][r][1]);
            }
        }
    }
    __syncthreads();   // all quarters done reading the vertex tables

    // --- Phase 3: desc[jl][f][k] in LDS, merge vertex-quarters ---
    for (int i = tid; i < 4 * NF * NK; i += 128) smem[i] = 0.0f;
    __syncthreads();
#pragma unroll
    for (int f = 0; f < 5; ++f)
#pragma unroll
        for (int r = 0; r < 5; ++r) {
            int idx = (jl * 5 + f) * NK + r * 16 + t0;
            atomicAdd(&smem[idx],     acc[f][r][0]);
            atomicAdd(&smem[idx + 1], acc[f][r][1]);
        }
    __syncthreads();

    // --- Phase 4: cf = desc . W for this quarter's 4 rotations, max, merge ---
    if (tid < 100) {
        const int f  = tid / 20;          // feature
        const int jo = (tid % 20) * 4;    // output bins jo..jo+3

        float a2[4][4];
#pragma unroll
        for (int jj = 0; jj < 4; ++jj)
#pragma unroll
            for (int qq = 0; qq < 4; ++qq) a2[jj][qq] = 0.0f;

        const float* Wf = Wc + f * (NK * NK) + jo;
        for (int k4 = 0; k4 < 20; ++k4) {
            const float* wp = Wf + (k4 * 4) * NK;
            float4 w0 = *(const float4*)(wp);
            float4 w1 = *(const float4*)(wp + NK);
            float4 w2 = *(const float4*)(wp + 2 * NK);
            float4 w3 = *(const float4*)(wp + 3 * NK);
#pragma unroll
            for (int jj = 0; jj < 4; ++jj) {
                float4 d4 = smem4[(jj * 5 + f) * 20 + k4];   // broadcast read
                a2[jj][0] = fmaf(d4.x, w0.x, a2[jj][0]);
                a2[jj][0] = fmaf(d4.y, w1.x, a2[jj][0]);
                a2[jj][0] = fmaf(d4.z, w2.x, a2[jj][0]);
                a2[jj][0] = fmaf(d4.w, w3.x, a2[jj][0]);
                a2[jj][1] = fmaf(d4.x, w0.y, a2[jj][1]);
                a2[jj][1] = fmaf(d4.y, w1.y, a2[jj][1]);
                a2[jj][1] = fmaf(d4.z, w2.y, a2[jj][1]);
                a2[jj][1] = fmaf(d4.w, w3.y, a2[jj][1]);
                a2[jj][2] = fmaf(d4.x, w0.z, a2[jj][2]);
                a2[jj][2] = fmaf(d4.y, w1.z, a2[jj][2]);
                a2[jj][2] = fmaf(d4.z, w2.z, a2[jj][2]);
                a2[jj][2] = fmaf(d4.w, w3.z, a2[jj][2]);
                a2[jj][3] = fmaf(d4.x, w0.w, a2[jj][3]);
                a2[jj][3] = fmaf(d4.y, w1.w, a2[jj][3]);
                a2[jj][3] = fmaf(d4.z, w2.w, a2[jj][3]);
                a2[jj][3] = fmaf(d4.w, w3.w, a2[jj][3]);
            }
        }

        int* ob = (int*)(out + (size_t)s * (NK * NF));
#pragma unroll
        for (int qq = 0; qq < 4; ++qq) {
            float m = fmaxf(fmaxf(a2[0][qq], a2[1][qq]),
                            fmaxf(a2[2][qq], a2[3][qq]));
            float val = fmaxf(m + bc[f * NK + jo + qq], 0.0f);
            atomicMax(&ob[(jo + qq) * NF + f], __float_as_int(val));
        }
    }
}

extern "C" void kernel_launch(void* const* d_in, const int* in_sizes, int n_in,
                              void* d_out, int out_size, void* d_ws, size_t ws_size,
                              hipStream_t stream) {
    const float* x           = (const float*)d_in[0];
    const float* mu_rho      = (const float*)d_in[1];
    const float* sigma_rho   = (const float*)d_in[2];
    const float* mu_theta    = (const float*)d_in[3];
    const float* sigma_theta = (const float*)d_in[4];
    const float* Wc          = (const float*)d_in[5];
    const float* bc          = (const float*)d_in[6];
    float* out = (float*)d_out;

    lsres_fused<<<dim3(NS * 4), dim3(128), 0, stream>>>(
        x, mu_rho, sigma_rho, mu_theta, sigma_theta, Wc, bc, out);
}

// Round 5
// 257.735 us; speedup vs baseline: 1.0479x; 1.0479x over previous
//
#include <hip/hip_runtime.h>
#include <math.h>

#define NS 1000
#define NV 200
#define NF 5
#define NK 80
#define EPSF 1e-5f

// fp32(2*pi); reference wraps with jnp.mod(x, 2pi) in f32.
#define TWOPI_F 6.28318530717958647692f
// fp32(2*pi/16) -- the scan multiplies fp32(j) by this constant.
#define STEP_F  0.39269908169872414f

static __device__ __forceinline__ float frcp(float v) {
    return __builtin_amdgcn_rcpf(v);
}

// 4 blocks per sample (rotation quarters), 128 threads (2 waves).
//
// CODEGEN NOTE (R1-R4 post-mortem): the AMDGPU backend derives its occupancy
// target from LDS-limited blocks/CU and caps the VGPR budget to 512/target:
//   R1: 25.6KB LDS -> 3 waves/SIMD target -> budget 168 -> VGPR 84, no spill
//   R2/R3/R4: small LDS or min-waves hints -> 8 waves/SIMD -> budget 64 ->
//   the 50-float desc accumulator spills (VGPR 40-48, WRITE_SIZE 17-24MB,
//   dur 204-270us). Phase 2 needs ~105 live VGPRs.
// Fix: pin the target at 4 waves/SIMD (budget 128) two redundant ways:
//   (a) pad LDS to 20000B -> 8 blocks/CU x 2 waves = 4 waves/SIMD,
//   (b) amdgpu_waves_per_eu(1,4).
// Scale TLP with MORE BLOCKS only (4000 x 2 waves = 31 waves/CU available).
//
//   thread = (q, jl, tp): q = tid>>5 vertex quarter (50 v), jl = (tid>>3)&3
//   local rotation (global j = jq*4 + jl), tp = tid&7 theta-pair.
// Phase 1: per-vertex tables -> LDS (12 floats per vertex).
// Phase 2: accumulate desc quarter-partials, 50 fp32 regs per thread.
// Phase 3: zero desc LDS, merge vertex-quarters via ds_add_f32.
// Phase 4: thread = (f, jo-quad), 100 active: cf = desc . W, max over the
//          4 local rotations, +b, relu, merge rotation-blocks via int
//          atomicMax on out (post-relu vals >= 0: int order == float order;
//          memset-0 and 0xAA poison both lose as signed int).
__global__ __attribute__((amdgpu_waves_per_eu(1, 4))) __launch_bounds__(128)
void lsres_fused(
        const float* __restrict__ x,
        const float* __restrict__ mu_rho,
        const float* __restrict__ sigma_rho,
        const float* __restrict__ mu_theta,
        const float* __restrict__ sigma_theta,
        const float* __restrict__ Wc,
        const float* __restrict__ bc,
        float* __restrict__ out) {
    // 5000 floats = 20.0 KB (deliberately padded -- see codegen note).
    // Phase-1/2 vertex tables use the first 2400 floats (600 float4); after
    // phase 2 the first 1600 floats are reused as desc[4][5][80].
    __shared__ float smem[5000];
    float4* smem4 = (float4*)smem;

    const int bid = blockIdx.x;
    const int s   = bid >> 2;
    const int jq  = bid & 3;           // rotation quarter 0..3
    const int tid = threadIdx.x;
    const int q   = tid >> 5;          // vertex quarter 0..3
    const int jl  = (tid >> 3) & 3;    // local rotation 0..3
    const int tp  = tid & 7;           // theta-pair 0..7
    const int t0  = tp * 2;            // theta bins t0, t0+1
    const int jg  = jq * 4 + jl;       // global rotation 0..15

    // --- per-thread constants (theta-bin Gaussians; F rows are identical) ---
    const float mu0 = mu_theta[t0];
    const float mu1 = mu_theta[t0 + 1];
    const float sg0 = sigma_theta[t0];
    const float sg1 = sigma_theta[t0 + 1];
    const float ist0 = 1.0f / (sg0 * sg0 + EPSF);
    const float ist1 = 1.0f / (sg1 * sg1 + EPSF);
    const float joff = (float)jg * STEP_F;

    float mr[5], isr[5];
#pragma unroll
    for (int r = 0; r < 5; ++r) {
        mr[r] = mu_rho[r * 16];           // mu_rho[k] depends only on r = k/16
        float sr = sigma_rho[r * 16];
        isr[r] = 1.0f / (sr * sr + EPSF);
    }

    // --- Phase 1: vertex tables ---
    for (int v = tid; v < NV; v += 128) {
        const float* xe = x + ((size_t)s * NV + v) * 8;
        float4 x0 = *(const float4*)(xe);       // feat0..3
        float4 x1 = *(const float4*)(xe + 4);   // feat4, rho, theta, mask
        float rho = x1.y, theta = x1.z, mask = x1.w;
        float rg[5];
        float srg = 0.0f;
#pragma unroll
        for (int r = 0; r < 5; ++r) {
            float d = rho - mr[r];
            rg[r] = __expf(-d * d * isr[r]);
            srg += rg[r];
        }
        // act_norm = mask*Rg*T / (mask*sumRg*sumT + eps); fold mask into feat
        // and into the denominator term.
        smem4[v * 3 + 0] = make_float4(x0.x * mask, x0.y * mask, x0.z * mask, x0.w * mask);
        smem4[v * 3 + 1] = make_float4(x1.x * mask, rg[0], rg[1], rg[2]);
        smem4[v * 3 + 2] = make_float4(rg[3], rg[4], mask * srg, theta);
    }
    __syncthreads();

    // --- Phase 2: accumulate desc partials over this quarter's vertices ---
    float acc[5][5][2];
#pragma unroll
    for (int f = 0; f < 5; ++f)
#pragma unroll
        for (int r = 0; r < 5; ++r) {
            acc[f][r][0] = 0.0f;
            acc[f][r][1] = 0.0f;
        }

    const int vbase = q * (NV / 4);
    for (int vi = 0; vi < NV / 4; ++vi) {
        const int v = vbase + vi;
        float4 a  = smem4[v * 3 + 0];   // fm0..3       (broadcast-ish reads)
        float4 bv = smem4[v * 3 + 1];   // fm4, rg0..2
        float4 c  = smem4[v * 3 + 2];   // rg3, rg4, mask*sumRg, theta

        // th = mod(theta + j*step, 2pi); theta < 2pi, joff < 2pi, so one
        // conditional subtract reproduces the reference's f32 wrap decision.
        float th = c.w + joff;
        th = (th >= TWOPI_F) ? (th - TWOPI_F) : th;

        float d0 = th - mu0;
        float d1 = th - mu1;
        float T0 = __expf(-d0 * d0 * ist0);
        float T1 = __expf(-d1 * d1 * ist1);

        // sum of T over the 16 theta bins of rotation jg
        // (8-lane tp-group, 2 bins each; xor 1/2/4 stays inside the group)
        float sT = T0 + T1;
        sT += __shfl_xor(sT, 1);
        sT += __shfl_xor(sT, 2);
        sT += __shfl_xor(sT, 4);

        float inv = frcp(fmaf(c.z, sT, EPSF));
        float p0 = T0 * inv;
        float p1 = T1 * inv;

        float fm[5] = {a.x, a.y, a.z, a.w, bv.x};
        float rg[5] = {bv.y, bv.z, bv.w, c.x, c.y};
#pragma unroll
        for (int r = 0; r < 5; ++r) {
            float g0 = rg[r] * p0;
            float g1 = rg[r] * p1;
#pragma unroll
            for (int f = 0; f < 5; ++f) {
                acc[f][r][0] = fmaf(fm[f], g0, acc[f][r][0]);
                acc[f][r][1] = fmaf(fm[f], g1, acc[f][r][1]);
            }
        }
    }
    __syncthreads();   // all quarters done reading the vertex tables

    // --- Phase 3: desc[jl][f][k] in LDS, merge vertex-quarters ---
    for (int i = tid; i < 4 * NF * NK; i += 128) smem[i] = 0.0f;
    __syncthreads();
#pragma unroll
    for (int f = 0; f < 5; ++f)
#pragma unroll
        for (int r = 0; r < 5; ++r) {
            int idx = (jl * 5 + f) * NK + r * 16 + t0;
            atomicAdd(&smem[idx],     acc[f][r][0]);
            atomicAdd(&smem[idx + 1], acc[f][r][1]);
        }
    __syncthreads();

    // --- Phase 4: cf = desc . W for this quarter's 4 rotations, max, merge ---
    if (tid < 100) {
        const int f  = tid / 20;          // feature
        const int jo = (tid % 20) * 4;    // output bins jo..jo+3

        float a2[4][4];
#pragma unroll
        for (int jj = 0; jj < 4; ++jj)
#pragma unroll
            for (int qq = 0; qq < 4; ++qq) a2[jj][qq] = 0.0f;

        const float* Wf = Wc + f * (NK * NK) + jo;
        for (int k4 = 0; k4 < 20; ++k4) {
            const float* wp = Wf + (k4 * 4) * NK;
            float4 w0 = *(const float4*)(wp);
            float4 w1 = *(const float4*)(wp + NK);
            float4 w2 = *(const float4*)(wp + 2 * NK);
            float4 w3 = *(const float4*)(wp + 3 * NK);
#pragma unroll
            for (int jj = 0; jj < 4; ++jj) {
                float4 d4 = smem4[(jj * 5 + f) * 20 + k4];   // broadcast read
                a2[jj][0] = fmaf(d4.x, w0.x, a2[jj][0]);
                a2[jj][0] = fmaf(d4.y, w1.x, a2[jj][0]);
                a2[jj][0] = fmaf(d4.z, w2.x, a2[jj][0]);
                a2[jj][0] = fmaf(d4.w, w3.x, a2[jj][0]);
                a2[jj][1] = fmaf(d4.x, w0.y, a2[jj][1]);
                a2[jj][1] = fmaf(d4.y, w1.y, a2[jj][1]);
                a2[jj][1] = fmaf(d4.z, w2.y, a2[jj][1]);
                a2[jj][1] = fmaf(d4.w, w3.y, a2[jj][1]);
                a2[jj][2] = fmaf(d4.x, w0.z, a2[jj][2]);
                a2[jj][2] = fmaf(d4.y, w1.z, a2[jj][2]);
                a2[jj][2] = fmaf(d4.z, w2.z, a2[jj][2]);
                a2[jj][2] = fmaf(d4.w, w3.z, a2[jj][2]);
                a2[jj][3] = fmaf(d4.x, w0.w, a2[jj][3]);
                a2[jj][3] = fmaf(d4.y, w1.w, a2[jj][3]);
                a2[jj][3] = fmaf(d4.z, w2.w, a2[jj][3]);
                a2[jj][3] = fmaf(d4.w, w3.w, a2[jj][3]);
            }
        }

        int* ob = (int*)(out + (size_t)s * (NK * NF));
#pragma unroll
        for (int qq = 0; qq < 4; ++qq) {
            float m = fmaxf(fmaxf(a2[0][qq], a2[1][qq]),
                            fmaxf(a2[2][qq], a2[3][qq]));
            float val = fmaxf(m + bc[f * NK + jo + qq], 0.0f);
            atomicMax(&ob[(jo + qq) * NF + f], __float_as_int(val));
        }
    }
}

extern "C" void kernel_launch(void* const* d_in, const int* in_sizes, int n_in,
                              void* d_out, int out_size, void* d_ws, size_t ws_size,
                              hipStream_t stream) {
    const float* x           = (const float*)d_in[0];
    const float* mu_rho      = (const float*)d_in[1];
    const float* sigma_rho   = (const float*)d_in[2];
    const float* mu_theta    = (const float*)d_in[3];
    const float* sigma_theta = (const float*)d_in[4];
    const float* Wc          = (const float*)d_in[5];
    const float* bc          = (const float*)d_in[6];
    float* out = (float*)d_out;

    lsres_fused<<<dim3(NS * 4), dim3(128), 0, stream>>>(
        x, mu_rho, sigma_rho, mu_theta, sigma_theta, Wc, bc, out);
}

// Round 6
// 158.003 us; speedup vs baseline: 1.7094x; 1.6312x over previous
//
#include <hip/hip_runtime.h>
#include <math.h>

#define NS 1000
#define NV 200
#define NF 5
#define NK 80
#define EPSF 1e-5f

// fp32(2*pi); reference wraps with jnp.mod(x, 2pi) in f32.
#define TWOPI_F 6.28318530717958647692f
// fp32(2*pi/16) -- the scan multiplies fp32(j) by this constant.
#define STEP_F  0.39269908169872414f

static __device__ __forceinline__ float frcp(float v) {
    return __builtin_amdgcn_rcpf(v);
}

// One block per sample, 256 threads (4 waves). thread = (j, t):
// j = tid>>4 rotation 0..15, t = tid&15 theta bin. 25 accumulators.
//
// CODEGEN NOTE (R1-R5 post-mortem): the AMDGPU backend caps the VGPR budget
// at 512 / (LDS-limited waves-per-SIMD over the 160KB pool); hints
// (launch_bounds min-waves, amdgpu_waves_per_eu) could not raise it. A
// 50-float accumulator (R2-R5 variants) spills whenever LDS is small
// (VGPR 40-52, WRITE_SIZE 17-24MB scratch, 204-270us vs R1 91us). Fix is
// structural: 25 accumulators per thread (~65 live VGPRs) + LDS padded to
// 32KB -> 4 blocks/CU target -> budget 128, need << budget. Runtime
// occupancy is grid-limited (1000 blocks ~= 3.9 blocks/CU = 15.6 waves/CU,
// 2x R1's). Do not shrink LDS below ~26KB and do not add occupancy hints.
//
// Phase 1: per-vertex tables -> LDS (12 floats per vertex, 200 threads).
// Phase 2: each thread: its theta-bin Gaussian, 16-lane butterfly for the
//          theta-sum, 25 fma/vertex into acc[f][r], all 200 vertices.
// Phase 3: plain stores desc[j][f][r*16+t] (unique owner, no atomics).
// Phase 4: thread = (f, jo-pair), 200 active: cf = desc . W, max over all
//          16 rotations, +b, relu, plain store out[s][jout][f].
__global__ __launch_bounds__(256) void lsres_fused(
        const float* __restrict__ x,
        const float* __restrict__ mu_rho,
        const float* __restrict__ sigma_rho,
        const float* __restrict__ mu_theta,
        const float* __restrict__ sigma_theta,
        const float* __restrict__ Wc,
        const float* __restrict__ bc,
        float* __restrict__ out) {
    // 8192 floats = 32 KB, deliberately padded (see codegen note).
    // Phase 1/2: first 2400 floats = vertex tables (600 float4).
    // Phase 3/4: first 6400 floats = desc[16][5][80].
    __shared__ float smem[8192];
    float4* smem4 = (float4*)smem;

    const int s   = blockIdx.x;
    const int tid = threadIdx.x;
    const int j   = tid >> 4;    // rotation 0..15
    const int t   = tid & 15;    // theta bin 0..15

    // --- per-thread constants (theta Gaussian of bin t; F rows identical) ---
    const float mu  = mu_theta[t];
    const float sg  = sigma_theta[t];
    const float ist = 1.0f / (sg * sg + EPSF);
    const float joff = (float)j * STEP_F;

    float mr[5], isr[5];
#pragma unroll
    for (int r = 0; r < 5; ++r) {
        mr[r] = mu_rho[r * 16];          // mu_rho[k] depends only on r = k/16
        float sr = sigma_rho[r * 16];
        isr[r] = 1.0f / (sr * sr + EPSF);
    }

    // --- Phase 1: vertex tables ---
    if (tid < NV) {
        const int v = tid;
        const float* xe = x + ((size_t)s * NV + v) * 8;
        float4 x0 = *(const float4*)(xe);       // feat0..3
        float4 x1 = *(const float4*)(xe + 4);   // feat4, rho, theta, mask
        float rho = x1.y, theta = x1.z, mask = x1.w;
        float rg[5];
        float srg = 0.0f;
#pragma unroll
        for (int r = 0; r < 5; ++r) {
            float d = rho - mr[r];
            rg[r] = __expf(-d * d * isr[r]);
            srg += rg[r];
        }
        // act_norm = mask*Rg*T / (mask*sumRg*sumT + eps); fold mask into feat
        // and into the denominator term.
        smem4[v * 3 + 0] = make_float4(x0.x * mask, x0.y * mask, x0.z * mask, x0.w * mask);
        smem4[v * 3 + 1] = make_float4(x1.x * mask, rg[0], rg[1], rg[2]);
        smem4[v * 3 + 2] = make_float4(rg[3], rg[4], mask * srg, theta);
    }
    __syncthreads();

    // --- Phase 2: accumulate desc over all vertices (25 accumulators) ---
    float acc[5][5];
#pragma unroll
    for (int f = 0; f < 5; ++f)
#pragma unroll
        for (int r = 0; r < 5; ++r) acc[f][r] = 0.0f;

#pragma unroll 2
    for (int v = 0; v < NV; ++v) {
        float4 a  = smem4[v * 3 + 0];   // fm0..3   (wave-broadcast reads)
        float4 bv = smem4[v * 3 + 1];   // fm4, rg0..2
        float4 c  = smem4[v * 3 + 2];   // rg3, rg4, mask*sumRg, theta

        // th = mod(theta + j*step, 2pi); theta < 2pi, joff < 2pi, so one
        // conditional subtract reproduces the reference's f32 wrap decision.
        float th = c.w + joff;
        th = (th >= TWOPI_F) ? (th - TWOPI_F) : th;

        float d = th - mu;
        float T = __expf(-d * d * ist);

        // sum of T over the 16 theta bins of rotation j
        // (16-lane t-group: xor 1,2,4,8 stays inside the group)
        float sT = T;
        sT += __shfl_xor(sT, 1);
        sT += __shfl_xor(sT, 2);
        sT += __shfl_xor(sT, 4);
        sT += __shfl_xor(sT, 8);

        float inv = frcp(fmaf(c.z, sT, EPSF));
        float p = T * inv;

        float fm[5] = {a.x, a.y, a.z, a.w, bv.x};
        float rg[5] = {bv.y, bv.z, bv.w, c.x, c.y};
#pragma unroll
        for (int r = 0; r < 5; ++r) {
            float g = rg[r] * p;
#pragma unroll
            for (int f = 0; f < 5; ++f)
                acc[f][r] = fmaf(fm[f], g, acc[f][r]);
        }
    }
    __syncthreads();   // everyone done reading the vertex tables

    // --- Phase 3: desc[j][f][r*16+t], unique owner per element ---
#pragma unroll
    for (int f = 0; f < 5; ++f)
#pragma unroll
        for (int r = 0; r < 5; ++r)
            smem[(j * 5 + f) * NK + r * 16 + t] = acc[f][r];
    __syncthreads();

    // --- Phase 4: cf = desc . W, max over 16 rotations, +b, relu ---
    if (tid < 200) {
        const int f  = tid / 40;          // feature
        const int jo = (tid % 40) * 2;    // output bins jo, jo+1 (coalesced W)

        float a2[16][2];
#pragma unroll
        for (int jj = 0; jj < 16; ++jj) { a2[jj][0] = 0.0f; a2[jj][1] = 0.0f; }

        const float* Wf = Wc + f * (NK * NK) + jo;
        for (int k4 = 0; k4 < 20; ++k4) {
            const float* wp = Wf + (k4 * 4) * NK;
            float2 w0 = *(const float2*)(wp);
            float2 w1 = *(const float2*)(wp + NK);
            float2 w2 = *(const float2*)(wp + 2 * NK);
            float2 w3 = *(const float2*)(wp + 3 * NK);
#pragma unroll
            for (int jj = 0; jj < 16; ++jj) {
                float4 d4 = smem4[(jj * 5 + f) * 20 + k4];   // broadcast read
                a2[jj][0] = fmaf(d4.x, w0.x, a2[jj][0]);
                a2[jj][0] = fmaf(d4.y, w1.x, a2[jj][0]);
                a2[jj][0] = fmaf(d4.z, w2.x, a2[jj][0]);
                a2[jj][0] = fmaf(d4.w, w3.x, a2[jj][0]);
                a2[jj][1] = fmaf(d4.x, w0.y, a2[jj][1]);
                a2[jj][1] = fmaf(d4.y, w1.y, a2[jj][1]);
                a2[jj][1] = fmaf(d4.z, w2.y, a2[jj][1]);
                a2[jj][1] = fmaf(d4.w, w3.y, a2[jj][1]);
            }
        }

        float m0 = -INFINITY, m1 = -INFINITY;
#pragma unroll
        for (int jj = 0; jj < 16; ++jj) {
            m0 = fmaxf(m0, a2[jj][0]);
            m1 = fmaxf(m1, a2[jj][1]);
        }

        float v0 = fmaxf(m0 + bc[f * NK + jo],     0.0f);
        float v1 = fmaxf(m1 + bc[f * NK + jo + 1], 0.0f);
        float* ob = out + (size_t)s * (NK * NF);
        ob[jo * NF + f]       = v0;       // out[s][jout][f]
        ob[(jo + 1) * NF + f] = v1;
    }
}

extern "C" void kernel_launch(void* const* d_in, const int* in_sizes, int n_in,
                              void* d_out, int out_size, void* d_ws, size_t ws_size,
                              hipStream_t stream) {
    const float* x           = (const float*)d_in[0];
    const float* mu_rho      = (const float*)d_in[1];
    const float* sigma_rho   = (const float*)d_in[2];
    const float* mu_theta    = (const float*)d_in[3];
    const float* sigma_theta = (const float*)d_in[4];
    const float* Wc          = (const float*)d_in[5];
    const float* bc          = (const float*)d_in[6];
    float* out = (float*)d_out;

    lsres_fused<<<dim3(NS), dim3(256), 0, stream>>>(
        x, mu_rho, sigma_rho, mu_theta, sigma_theta, Wc, bc, out);
}